// Round 10
// baseline (14748.878 us; speedup 1.0000x reference)
//
#include <hip/hip_runtime.h>

#define NB 16          // batches
#define NPTS 131072    // points per batch
#define NPOINT 1024
#define HID 192
#define OUTC 384
#define PTS_PER_T 8
#define TAG_INIT 1023u   // tags run 0..1022, never 1023
#define TAGM 0x3FFu

static __device__ __forceinline__ unsigned long long ald_ag(const unsigned long long* p) {
  return __hip_atomic_load(p, __ATOMIC_RELAXED, __HIP_MEMORY_SCOPE_AGENT);
}
static __device__ __forceinline__ void ast_ag(unsigned long long* p, unsigned long long v) {
  __hip_atomic_store(p, v, __ATOMIC_RELAXED, __HIP_MEMORY_SCOPE_AGENT);
}
__device__ __forceinline__ unsigned long long shflxor_max_u64(unsigned long long v, int off) {
  unsigned int lo = (unsigned int)v, hi = (unsigned int)(v >> 32);
  lo = __shfl_xor(lo, off, 64);
  hi = __shfl_xor(hi, off, 64);
  unsigned long long o = ((unsigned long long)hi << 32) | lo;
  return o > v ? o : v;
}

// LDS-only barrier: drain lgkmcnt, raw s_barrier. Prefetched global probe
// loads (vmcnt) stay in flight across it; __syncthreads would drain vmcnt(0).
__device__ __forceinline__ void bar_lds() {
  asm volatile("s_waitcnt lgkmcnt(0)" ::: "memory");
  __builtin_amdgcn_s_barrier();
}

// Check two prefetched probes; fall back to a fresh 2-deep retry loop.
__device__ __forceinline__ unsigned long long check2(
    unsigned long long q0, unsigned long long q1,
    const unsigned long long* pw, unsigned int uit)
{
  if (((unsigned int)q0 & TAGM) == uit) return q0;
  if (((unsigned int)q1 & TAGM) == uit) return q1;
  for (;;) {
    unsigned long long a0 = ald_ag(pw);
    unsigned long long a1 = ald_ag(pw);
    if (((unsigned int)a0 & TAGM) == uit) return a0;
    if (((unsigned int)a1 & TAGM) == uit) return a1;
  }
}

// detect + 4-step xor-max over lanes 0..15 -> global winner index
__device__ __forceinline__ int w_detect(
    unsigned long long q0, unsigned long long q1,
    const unsigned long long* pw, unsigned int uit)
{
  unsigned long long pv = check2(q0, q1, pw, uit);
  pv = shflxor_max_u64(pv, 8);
  pv = shflxor_max_u64(pv, 4);
  pv = shflxor_max_u64(pv, 2);
  pv = shflxor_max_u64(pv, 1);
  return NPTS - 1 - (int)((pv >> 15) & 0x1FFFFull);
}

// md update for one chain (coords re-read from L2-resident private slice;
// addresses are SGPR-base + precomputed byte offset, zero per-iter VALU),
// then 6-step wave reduce. Returns wave-winner key (valid in lane 0).
__device__ __forceinline__ unsigned long long upd_chain(
    const float* __restrict__ BP, unsigned int off0, unsigned int idx0,
    float (&md)[PTS_PER_T], float lx, float ly, float lz)
{
  float bm = -1.0f; int bk = 0;
#pragma unroll
  for (int k = 0; k < PTS_PER_T; ++k) {
    const float* p = (const float*)((const char*)BP + (off0 + 12288u * (unsigned)k));
    float x = p[0], y = p[1], z = p[2];
    float dx = x - lx, dy = y - ly, dz = z - lz;
    // numpy op order, no FMA contraction: (dx*dx + dy*dy) + dz*dz
    float d = __fadd_rn(__fadd_rn(__fmul_rn(dx, dx), __fmul_rn(dy, dy)), __fmul_rn(dz, dz));
    float m = fminf(md[k], d);
    md[k] = m;
    if (m > bm) { bm = m; bk = k; }   // strict >: smallest k == smallest idx
  }
  unsigned int idx = idx0 + ((unsigned)bk << 10);
  unsigned long long key = ((unsigned long long)__float_as_uint(bm) << 32)
                         | ((unsigned long long)(NPTS - 1 - idx) << 15);
#pragma unroll
  for (int off = 32; off > 0; off >>= 1) {
    unsigned int lo = (unsigned int)key, hi = (unsigned int)(key >> 32);
    lo = __shfl_down(lo, off, 64);
    hi = __shfl_down(hi, off, 64);
    unsigned long long o = ((unsigned long long)hi << 32) | lo;
    key = o > key ? o : key;
  }
  return key;
}

// ---------------- FPS: four phase-shifted chains per block ----------------
// 64 blocks. Block j serves slice r=j&15 of batches 4*(j>>4)+{0,1,2,3}.
// Per (batch,parity): one 128B line of 16 tagged keys (round-8 protocol).
// Loop = 4 phases; phase q: publish chain q-1 (tag n+1; W0 publishes chain3
// tag n), prefetch chain q+1's probes, detect chain q (tag n), resolve winner
// coords, then all-wave update of chain q. Every chain: pub -> detect = 3
// phases (~1.8us > visible+RT), prefetch 2 phases after pub, 1 phase in
// flight. Raw s_barrier + lgkmcnt keeps probes alive across barriers.
// Skew safety: pub(c,n+2) is program-order-after det(c,n+1), which requires
// every block's pub(c,n+1), each after that block's det(c,n) -> the parity
// line being overwritten is globally consumed.
__global__ __launch_bounds__(1024) void fps_kernel(
    const float* __restrict__ points,
    unsigned long long* __restrict__ slots,   // [NB][2][16]
    int* __restrict__ fps_idx)                // [NB][NPOINT], [b][0]=0 pre-set
{
  const int j = blockIdx.x;       // 0..63
  const int g = j >> 4;           // 0..3
  const int r = j & 15;
  const int t = threadIdx.x;
  const int lane = t & 63, wid = t >> 6;
  const int b0 = g * 4, b1 = b0 + 1, b2 = b0 + 2, b3 = b0 + 3;
  const float* __restrict__ BP0 = points + (size_t)b0 * NPTS * 3;
  const float* __restrict__ BP1 = points + (size_t)b1 * NPTS * 3;
  const float* __restrict__ BP2 = points + (size_t)b2 * NPTS * 3;
  const float* __restrict__ BP3 = points + (size_t)b3 * NPTS * 3;
  unsigned long long* reg0 = slots + (size_t)b0 * 32;   // [2][16]
  unsigned long long* reg1 = slots + (size_t)b1 * 32;
  unsigned long long* reg2 = slots + (size_t)b2 * 32;
  unsigned long long* reg3 = slots + (size_t)b3 * 32;
  const unsigned int idx0 = ((unsigned)r << 13) + (unsigned)t;
  const unsigned int off0 = idx0 * 12u;

  float md0[PTS_PER_T], md1[PTS_PER_T], md2[PTS_PER_T], md3[PTS_PER_T];
#pragma unroll
  for (int k = 0; k < PTS_PER_T; ++k) {
    md0[k] = 1e10f; md1[k] = 1e10f; md2[k] = 1e10f; md3[k] = 1e10f;
  }

  __shared__ unsigned long long s_red[4][16];
  __shared__ float s_w[4][4];

  // ---- prologue: iteration 0, winner = point 0 of each batch ----
  {
    unsigned long long k0 = upd_chain(BP0, off0, idx0, md0, BP0[0], BP0[1], BP0[2]);
    unsigned long long k1 = upd_chain(BP1, off0, idx0, md1, BP1[0], BP1[1], BP1[2]);
    unsigned long long k2 = upd_chain(BP2, off0, idx0, md2, BP2[0], BP2[1], BP2[2]);
    unsigned long long k3 = upd_chain(BP3, off0, idx0, md3, BP3[0], BP3[1], BP3[2]);
    if (lane == 0) {
      s_red[0][wid] = k0; s_red[1][wid] = k1; s_red[2][wid] = k2; s_red[3][wid] = k3;
    }
  }
  __syncthreads();

  unsigned long long q00 = 0, q01 = 0, q10 = 0, q11 = 0;
  unsigned long long q20 = 0, q21 = 0, q30 = 0, q31 = 0;

  if (wid == 0 && lane < 16) {
    // publish chains 0,1,2 (tag 0, parity 0); chain3 publishes in W0 of n=0
    unsigned long long kk0 = s_red[0][lane];
    kk0 = shflxor_max_u64(kk0, 8); kk0 = shflxor_max_u64(kk0, 4);
    kk0 = shflxor_max_u64(kk0, 2); kk0 = shflxor_max_u64(kk0, 1);
    unsigned long long kk1 = s_red[1][lane];
    kk1 = shflxor_max_u64(kk1, 8); kk1 = shflxor_max_u64(kk1, 4);
    kk1 = shflxor_max_u64(kk1, 2); kk1 = shflxor_max_u64(kk1, 1);
    unsigned long long kk2 = s_red[2][lane];
    kk2 = shflxor_max_u64(kk2, 8); kk2 = shflxor_max_u64(kk2, 4);
    kk2 = shflxor_max_u64(kk2, 2); kk2 = shflxor_max_u64(kk2, 1);
    if (lane == 0) {
      ast_ag(&reg0[r], kk0);   // tag 0
      ast_ag(&reg1[r], kk1);
      ast_ag(&reg2[r], kk2);
    }
    q00 = ald_ag(reg0 + lane);   // chain0 det(0) probes (parity 0)
    q01 = ald_ag(reg0 + lane);
  }

  // ---- main loop: n = 0..1021 (detect n, publish n+1) ----
  for (int n = 0; n < NPOINT - 2; ++n) {
    const unsigned int pd = (unsigned)(n & 1) * 16u;   // parity offset, tag n
    const unsigned int pn = pd ^ 16u;                  // parity offset, tag n+1
    const unsigned int un = (unsigned)n;
    const unsigned long long tgn  = (unsigned long long)un;
    const unsigned long long tgn1 = (unsigned long long)(un + 1u);

    // W0: pub chain3(tag n, pd); pref chain1(pd); det chain0(tag n, pd)
    if (wid == 0 && lane < 16) {
      unsigned long long kk = s_red[3][lane];
      kk = shflxor_max_u64(kk, 8); kk = shflxor_max_u64(kk, 4);
      kk = shflxor_max_u64(kk, 2); kk = shflxor_max_u64(kk, 1);
      if (lane == 0) ast_ag(reg3 + pd + r, kk | tgn);
      q10 = ald_ag(reg1 + pd + lane);
      q11 = ald_ag(reg1 + pd + lane);
      int gi = w_detect(q00, q01, reg0 + pd + lane, un);
      float c = 0.0f;
      if (lane < 3) c = BP0[3 * (size_t)gi + lane];
      if (lane == 0 && r == 0) fps_idx[b0 * NPOINT + n + 1] = gi;
      if (lane < 3) s_w[0][lane] = c;
    }
    bar_lds();
    {  // U0
      unsigned long long k = upd_chain(BP0, off0, idx0, md0, s_w[0][0], s_w[0][1], s_w[0][2]);
      if (lane == 0) s_red[0][wid] = k;
    }
    bar_lds();

    // W1: pub chain0(tag n+1, pn); pref chain2(pd); det chain1(tag n, pd)
    if (wid == 0 && lane < 16) {
      unsigned long long kk = s_red[0][lane];
      kk = shflxor_max_u64(kk, 8); kk = shflxor_max_u64(kk, 4);
      kk = shflxor_max_u64(kk, 2); kk = shflxor_max_u64(kk, 1);
      if (lane == 0) ast_ag(reg0 + pn + r, kk | tgn1);
      q20 = ald_ag(reg2 + pd + lane);
      q21 = ald_ag(reg2 + pd + lane);
      int gi = w_detect(q10, q11, reg1 + pd + lane, un);
      float c = 0.0f;
      if (lane < 3) c = BP1[3 * (size_t)gi + lane];
      if (lane == 0 && r == 0) fps_idx[b1 * NPOINT + n + 1] = gi;
      if (lane < 3) s_w[1][lane] = c;
    }
    bar_lds();
    {  // U1
      unsigned long long k = upd_chain(BP1, off0, idx0, md1, s_w[1][0], s_w[1][1], s_w[1][2]);
      if (lane == 0) s_red[1][wid] = k;
    }
    bar_lds();

    // W2: pub chain1(tag n+1, pn); pref chain3(pd); det chain2(tag n, pd)
    if (wid == 0 && lane < 16) {
      unsigned long long kk = s_red[1][lane];
      kk = shflxor_max_u64(kk, 8); kk = shflxor_max_u64(kk, 4);
      kk = shflxor_max_u64(kk, 2); kk = shflxor_max_u64(kk, 1);
      if (lane == 0) ast_ag(reg1 + pn + r, kk | tgn1);
      q30 = ald_ag(reg3 + pd + lane);
      q31 = ald_ag(reg3 + pd + lane);
      int gi = w_detect(q20, q21, reg2 + pd + lane, un);
      float c = 0.0f;
      if (lane < 3) c = BP2[3 * (size_t)gi + lane];
      if (lane == 0 && r == 0) fps_idx[b2 * NPOINT + n + 1] = gi;
      if (lane < 3) s_w[2][lane] = c;
    }
    bar_lds();
    {  // U2
      unsigned long long k = upd_chain(BP2, off0, idx0, md2, s_w[2][0], s_w[2][1], s_w[2][2]);
      if (lane == 0) s_red[2][wid] = k;
    }
    bar_lds();

    // W3: pub chain2(tag n+1, pn); pref chain0(pn: det(n+1)); det chain3(tag n, pd)
    if (wid == 0 && lane < 16) {
      unsigned long long kk = s_red[2][lane];
      kk = shflxor_max_u64(kk, 8); kk = shflxor_max_u64(kk, 4);
      kk = shflxor_max_u64(kk, 2); kk = shflxor_max_u64(kk, 1);
      if (lane == 0) ast_ag(reg2 + pn + r, kk | tgn1);
      q00 = ald_ag(reg0 + pn + lane);
      q01 = ald_ag(reg0 + pn + lane);
      int gi = w_detect(q30, q31, reg3 + pd + lane, un);
      float c = 0.0f;
      if (lane < 3) c = BP3[3 * (size_t)gi + lane];
      if (lane == 0 && r == 0) fps_idx[b3 * NPOINT + n + 1] = gi;
      if (lane < 3) s_w[3][lane] = c;
    }
    bar_lds();
    {  // U3
      unsigned long long k = upd_chain(BP3, off0, idx0, md3, s_w[3][0], s_w[3][1], s_w[3][2]);
      if (lane == 0) s_red[3][wid] = k;
    }
    bar_lds();
  }

  // ---- epilogue: detect tag 1022 (parity 0) for all chains ----
  if (wid == 0 && lane < 16) {
    const unsigned int ue = (unsigned)(NPOINT - 2);      // 1022
    unsigned long long kk = s_red[3][lane];
    kk = shflxor_max_u64(kk, 8); kk = shflxor_max_u64(kk, 4);
    kk = shflxor_max_u64(kk, 2); kk = shflxor_max_u64(kk, 1);
    if (lane == 0) ast_ag(reg3 + r, kk | (unsigned long long)ue);
    q10 = ald_ag(reg1 + lane); q11 = ald_ag(reg1 + lane);
    q20 = ald_ag(reg2 + lane); q21 = ald_ag(reg2 + lane);
    q30 = ald_ag(reg3 + lane); q31 = ald_ag(reg3 + lane);
    int gi0 = w_detect(q00, q01, reg0 + lane, ue);
    if (lane == 0 && r == 0) fps_idx[b0 * NPOINT + NPOINT - 1] = gi0;
    int gi1 = w_detect(q10, q11, reg1 + lane, ue);
    if (lane == 0 && r == 0) fps_idx[b1 * NPOINT + NPOINT - 1] = gi1;
    int gi2 = w_detect(q20, q21, reg2 + lane, ue);
    if (lane == 0 && r == 0) fps_idx[b2 * NPOINT + NPOINT - 1] = gi2;
    int gi3 = w_detect(q30, q31, reg3 + lane, ue);
    if (lane == 0 && r == 0) fps_idx[b3 * NPOINT + NPOINT - 1] = gi3;
  }
}

// ---------------- init ----------------
__global__ void fps_init_kernel(unsigned long long* __restrict__ slots,
                                int* __restrict__ fps_idx)
{
  int i = blockIdx.x * blockDim.x + threadIdx.x;
  if (i < NB * 2 * 16) slots[i] = (unsigned long long)TAG_INIT;
  if (i < NB) fps_idx[i * NPOINT] = 0;
}

// ---------------- MLP ----------------
// 4 rows (centers) per block, 384 threads. Phase 1: hidden (2 MLPs x 192)
// with exact GELU into LDS. Phase 2: thread o accumulates output column o.
__global__ __launch_bounds__(384) void mlp_kernel(
    const float* __restrict__ points,
    const int* __restrict__ fps_idx,
    const float* __restrict__ w1t, const float* __restrict__ b1t,
    const float* __restrict__ w2t, const float* __restrict__ b2t,
    const float* __restrict__ w1p, const float* __restrict__ b1p,
    const float* __restrict__ w2p, const float* __restrict__ b2p,
    float* __restrict__ out)
{
  __shared__ float s_c[4][3];
  __shared__ float s_h[2][HID][4];
  const int t = threadIdx.x;
  const int m0 = blockIdx.x * 4;
  if (t < 4) {
    int m = m0 + t;
    int b = m >> 10;
    int idx = fps_idx[m];
    const float* p = points + ((size_t)b * NPTS + (size_t)idx) * 3;
    s_c[t][0] = p[0]; s_c[t][1] = p[1]; s_c[t][2] = p[2];
  }
  __syncthreads();
  {
    const int mlp = t / HID;            // 0 = token, 1 = pos
    const int k = t - mlp * HID;
    const float* w1 = mlp ? w1p : w1t;
    const float* b1 = mlp ? b1p : b1t;
    float wa = w1[k], wb = w1[HID + k], wc = w1[2 * HID + k], bb = b1[k];
#pragma unroll
    for (int r = 0; r < 4; ++r) {
      float z = s_c[r][0] * wa + s_c[r][1] * wb + s_c[r][2] * wc + bb;
      float g = 0.5f * z * (1.0f + erff(z * 0.70710678118654752440f));
      s_h[mlp][k][r] = g;
    }
  }
  __syncthreads();
  const int o = t;
  float acct[4] = {0.f, 0.f, 0.f, 0.f};
  float accp[4] = {0.f, 0.f, 0.f, 0.f};
  const float* w2t_o = w2t + o;
  const float* w2p_o = w2p + o;
#pragma unroll 4
  for (int k = 0; k < HID; ++k) {
    float wt = w2t_o[(size_t)k * OUTC];
    float wp = w2p_o[(size_t)k * OUTC];
    float4 ht = *(const float4*)&s_h[0][k][0];
    float4 hp = *(const float4*)&s_h[1][k][0];
    acct[0] = fmaf(ht.x, wt, acct[0]);
    acct[1] = fmaf(ht.y, wt, acct[1]);
    acct[2] = fmaf(ht.z, wt, acct[2]);
    acct[3] = fmaf(ht.w, wt, acct[3]);
    accp[0] = fmaf(hp.x, wp, accp[0]);
    accp[1] = fmaf(hp.y, wp, accp[1]);
    accp[2] = fmaf(hp.z, wp, accp[2]);
    accp[3] = fmaf(hp.w, wp, accp[3]);
  }
  float bt = b2t[o], bp = b2p[o];
  const size_t posoff = (size_t)NB * NPOINT * OUTC;
#pragma unroll
  for (int rr = 0; rr < 4; ++rr) {
    size_t m = (size_t)(m0 + rr);
    out[m * OUTC + o] = acct[rr] + bt;
    out[posoff + m * OUTC + o] = accp[rr] + bp;
  }
}

extern "C" void kernel_launch(void* const* d_in, const int* in_sizes, int n_in,
                              void* d_out, int out_size, void* d_ws, size_t ws_size,
                              hipStream_t stream)
{
  const float* points = (const float*)d_in[0];
  const float* w1t = (const float*)d_in[1];
  const float* b1t = (const float*)d_in[2];
  const float* w2t = (const float*)d_in[3];
  const float* b2t = (const float*)d_in[4];
  const float* w1p = (const float*)d_in[5];
  const float* b1p = (const float*)d_in[6];
  const float* w2p = (const float*)d_in[7];
  const float* b2p = (const float*)d_in[8];
  float* out = (float*)d_out;

  char* ws = (char*)d_ws;
  unsigned long long* slots = (unsigned long long*)(ws + 0);  // 16*2*16*8 = 4096 B
  int* fps_idx = (int*)(ws + 4096);                           // 16*1024*4 = 65536 B

  hipLaunchKernelGGL(fps_init_kernel, dim3(2), dim3(256), 0, stream,
                     slots, fps_idx);

  void* args[3];
  args[0] = (void*)&points;
  args[1] = (void*)&slots;
  args[2] = (void*)&fps_idx;
  hipLaunchCooperativeKernel((void*)fps_kernel, dim3(64),
                             dim3(1024), args, 0, stream);

  hipLaunchKernelGGL(mlp_kernel, dim3(NB * NPOINT / 4), dim3(384), 0, stream,
                     points, fps_idx, w1t, b1t, w2t, b2t, w1p, b1p, w2p, b2p, out);
}